// Round 1
// baseline (2657.806 us; speedup 1.0000x reference)
//
#include <hip/hip_runtime.h>
#include <math.h>

#define B_GRAPHS 8192
#define OUT_DIM 1024
#define NU 128
#define NS 8
#define IN_DIM 1160          // OUT_DIM + NU + NS
#define HID 256
#define NSEG (B_GRAPHS * NU)        // 1048576 = 2^20
#define EDGES (B_GRAPHS * OUT_DIM)  // 8388608 = 2^23

// ---------- order-preserving float <-> uint map for atomicMax on floats ----
__device__ __forceinline__ unsigned f2o(float f) {
    unsigned u = __float_as_uint(f);
    return (u & 0x80000000u) ? ~u : (u | 0x80000000u);
}
__device__ __forceinline__ float o2f(unsigned o) {
    return __uint_as_float((o & 0x80000000u) ? (o & 0x7fffffffu) : ~o);
}

// ---------------- tiled fp32 GEMM: C = act(A @ W + bias) -------------------
// BM=BN=64, BK=16, 256 threads, 4x4 micro-tile per thread.
#define BM 64
#define BN 64
#define BK 16

enum { A_PLAIN = 0, A_FEATS = 1 };
enum { EPI_RELU = 0, EPI_SCHES = 1 };

template <int AMODE, int EPI>
__global__ __launch_bounds__(256) void gemm_kernel(
    const float* __restrict__ A,
    const float* __restrict__ u2s, const float* __restrict__ usr,
    const float* __restrict__ srv,
    const float* __restrict__ W, const float* __restrict__ bias,
    float* __restrict__ Cout, int M, int N, int K)
{
    __shared__ float As[BK][BM + 4];  // k-major so compute reads are float4
    __shared__ float Bs[BK][BN + 4];

    const int tid = threadIdx.x;
    const int tx = tid & 15;   // 0..15 -> N
    const int ty = tid >> 4;   // 0..15 -> M
    const int m0 = blockIdx.y * BM;
    const int n0 = blockIdx.x * BN;

    // A loader: thread -> (row, 4 consecutive k)
    const int a_row = tid >> 2;        // 0..63
    const int a_col = (tid & 3) * 4;   // 0,4,8,12
    // B loader: thread -> (k row, 4 consecutive n)
    const int b_row = tid >> 4;        // 0..15
    const int b_col = (tid & 15) * 4;  // 0..60

    float acc[4][4] = {{0.f}};

    for (int k0 = 0; k0 < K; k0 += BK) {
        // ---- stage A tile ----
        if (AMODE == A_PLAIN) {
            // K multiple of 16 and rows 16B-aligned in all plain uses (K=256)
            const float4 v = *reinterpret_cast<const float4*>(
                &A[(size_t)(m0 + a_row) * K + k0 + a_col]);
            As[a_col + 0][a_row] = v.x;
            As[a_col + 1][a_row] = v.y;
            As[a_col + 2][a_row] = v.z;
            As[a_col + 3][a_row] = v.w;
        } else {
            const int row = m0 + a_row;
#pragma unroll
            for (int i = 0; i < 4; ++i) {
                const int k = k0 + a_col + i;
                float v = 0.f;
                if (k < OUT_DIM)           v = u2s[(size_t)row * OUT_DIM + k];
                else if (k < OUT_DIM + NU) v = usr[(size_t)row * NU + (k - OUT_DIM)];
                else if (k < IN_DIM)       v = srv[(size_t)row * NS + (k - OUT_DIM - NU)];
                As[a_col + i][a_row] = v;
            }
        }
        // ---- stage B tile (W is K x N row-major) ----
        {
            const int k = k0 + b_row;
            float4 v = make_float4(0.f, 0.f, 0.f, 0.f);
            if (k < K)
                v = *reinterpret_cast<const float4*>(&W[(size_t)k * N + n0 + b_col]);
            Bs[b_row][b_col + 0] = v.x;
            Bs[b_row][b_col + 1] = v.y;
            Bs[b_row][b_col + 2] = v.z;
            Bs[b_row][b_col + 3] = v.w;
        }
        __syncthreads();

#pragma unroll
        for (int kk = 0; kk < BK; ++kk) {
            const float4 av = *reinterpret_cast<const float4*>(&As[kk][ty * 4]);
            const float4 bv = *reinterpret_cast<const float4*>(&Bs[kk][tx * 4]);
            const float a[4] = {av.x, av.y, av.z, av.w};
            const float b[4] = {bv.x, bv.y, bv.z, bv.w};
#pragma unroll
            for (int i = 0; i < 4; ++i)
#pragma unroll
                for (int j = 0; j < 4; ++j)
                    acc[i][j] = fmaf(a[i], b[j], acc[i][j]);
        }
        __syncthreads();
    }

    // ---- epilogue ----
#pragma unroll
    for (int i = 0; i < 4; ++i) {
        const int row = m0 + ty * 4 + i;
#pragma unroll
        for (int j = 0; j < 4; ++j) {
            const int col = n0 + tx * 4 + j;
            const float v = acc[i][j] + bias[col];
            if (EPI == EPI_RELU) {
                Cout[(size_t)row * N + col] = fmaxf(v, 0.f);
            } else {
                // sches column -> (section, within); store so each section is
                // a contiguous [B, OUT] block of d_out matching return order.
                const int sec = col >> 10;          // /1024
                const int within = col & 1023;      // %1024
                Cout[(size_t)sec * EDGES + (size_t)row * OUT_DIM + within] = v;
            }
        }
    }
}

// ---------------- scatter softmax passes -----------------------------------
__global__ __launch_bounds__(256) void init_ms_kernel(unsigned* __restrict__ m,
                                                      float* __restrict__ s) {
    const int i = blockIdx.x * blockDim.x + threadIdx.x;
    if (i < 3 * NSEG) {
        m[i] = f2o(-INFINITY);
        s[i] = 0.f;
    }
}

__global__ __launch_bounds__(256) void segmax_kernel(
    const float* __restrict__ vals, const int* __restrict__ idx0,
    const int* __restrict__ idx1, unsigned* __restrict__ m) {
    const int i = blockIdx.x * blockDim.x + threadIdx.x;
    if (i >= 3 * EDGES) return;
    const int sec = i >> 23;          // / EDGES
    const int w = i & (EDGES - 1);    // % EDGES
    const int idx = (sec < 2) ? idx0[w] : idx1[w];
    atomicMax(&m[sec * NSEG + idx], f2o(vals[i]));
}

__global__ __launch_bounds__(256) void segexp_kernel(
    float* __restrict__ vals, const int* __restrict__ idx0,
    const int* __restrict__ idx1, const unsigned* __restrict__ m,
    float* __restrict__ s) {
    const int i = blockIdx.x * blockDim.x + threadIdx.x;
    if (i >= 3 * EDGES) return;
    const int sec = i >> 23;
    const int w = i & (EDGES - 1);
    const int idx = (sec < 2) ? idx0[w] : idx1[w];
    const float e = expf(vals[i] - o2f(m[sec * NSEG + idx]));
    vals[i] = e;
    atomicAdd(&s[sec * NSEG + idx], e);
}

__global__ __launch_bounds__(256) void segdiv_kernel(
    float* __restrict__ vals, const int* __restrict__ idx0,
    const int* __restrict__ idx1, const float* __restrict__ s) {
    const int i = blockIdx.x * blockDim.x + threadIdx.x;
    if (i >= 3 * EDGES) return;
    const int sec = i >> 23;
    const int w = i & (EDGES - 1);
    const int idx = (sec < 2) ? idx0[w] : idx1[w];
    vals[i] = vals[i] / s[sec * NSEG + idx];
}

// ---------------------------------------------------------------------------
extern "C" void kernel_launch(void* const* d_in, const int* in_sizes, int n_in,
                              void* d_out, int out_size, void* d_ws,
                              size_t ws_size, hipStream_t stream) {
    const float* u2s = (const float*)d_in[0];
    const float* usr = (const float*)d_in[1];
    const float* srv = (const float*)d_in[2];
    const int* edge = (const int*)d_in[3];
    const float* W1 = (const float*)d_in[4];
    const float* b1 = (const float*)d_in[5];
    const float* W2 = (const float*)d_in[6];
    const float* b2 = (const float*)d_in[7];
    const float* W3 = (const float*)d_in[8];
    const float* b3 = (const float*)d_in[9];
    const float* W4 = (const float*)d_in[10];
    const float* b4 = (const float*)d_in[11];

    const int* idx0 = edge;
    const int* idx1 = edge + EDGES;

    // workspace layout: h1,h2,h3 (2M floats each) | m (3M uints) | s (3M floats)
    float* h1 = (float*)d_ws;
    float* h2 = h1 + (size_t)B_GRAPHS * HID;
    float* h3 = h2 + (size_t)B_GRAPHS * HID;
    unsigned* m = (unsigned*)(h3 + (size_t)B_GRAPHS * HID);
    float* s = (float*)(m + 3 * NSEG);
    float* outp = (float*)d_out;

    const dim3 blk(256);

    // GEMM1: feats(8192x1160) @ W1(1160x256) -> relu -> h1
    gemm_kernel<A_FEATS, EPI_RELU>
        <<<dim3(HID / BN, B_GRAPHS / BM), blk, 0, stream>>>(
            nullptr, u2s, usr, srv, W1, b1, h1, B_GRAPHS, HID, IN_DIM);
    // GEMM2: h1 @ W2 -> relu -> h2
    gemm_kernel<A_PLAIN, EPI_RELU>
        <<<dim3(HID / BN, B_GRAPHS / BM), blk, 0, stream>>>(
            h1, nullptr, nullptr, nullptr, W2, b2, h2, B_GRAPHS, HID, HID);
    // GEMM3: h2 @ W3 -> relu -> h3
    gemm_kernel<A_PLAIN, EPI_RELU>
        <<<dim3(HID / BN, B_GRAPHS / BM), blk, 0, stream>>>(
            h2, nullptr, nullptr, nullptr, W3, b3, h3, B_GRAPHS, HID, HID);
    // GEMM4: h3 @ W4(256x3072) + b4 -> d_out (remapped into 3 sections)
    gemm_kernel<A_PLAIN, EPI_SCHES>
        <<<dim3(3 * OUT_DIM / BN, B_GRAPHS / BM), blk, 0, stream>>>(
            h3, nullptr, nullptr, nullptr, W4, b4, outp, B_GRAPHS, 3 * OUT_DIM,
            HID);

    // scatter softmax over segments, in place on d_out
    init_ms_kernel<<<(3 * NSEG + 255) / 256, blk, 0, stream>>>(m, s);
    const int total = 3 * EDGES;
    segmax_kernel<<<(total + 255) / 256, blk, 0, stream>>>(outp, idx0, idx1, m);
    segexp_kernel<<<(total + 255) / 256, blk, 0, stream>>>(outp, idx0, idx1, m, s);
    segdiv_kernel<<<(total + 255) / 256, blk, 0, stream>>>(outp, idx0, idx1, s);
}

// Round 2
// 1661.045 us; speedup vs baseline: 1.6001x; 1.6001x over previous
//
#include <hip/hip_runtime.h>
#include <math.h>

#define B_GRAPHS 8192
#define OUT_DIM 1024
#define NU 128
#define NS 8
#define IN_DIM 1160          // OUT_DIM + NU + NS
#define HID 256
#define NSEG (B_GRAPHS * NU)        // 1048576 = 2^20
#define EDGES (B_GRAPHS * OUT_DIM)  // 8388608 = 2^23

// ---------------- tiled fp32 GEMM: C = act(A @ W + bias) -------------------
// BM=BN=64, BK=16, 256 threads, 4x4 micro-tile per thread.
#define BM 64
#define BN 64
#define BK 16

enum { A_PLAIN = 0, A_FEATS = 1 };
enum { EPI_RELU = 0, EPI_SCHES = 1 };

// EPI_SCHES: out gets exp(v); segment sums accumulated via atomics:
//   sections 0,1 (idx0): s01[2*idx + sec]   (interleaved -> same 64B line)
//   section  2  (idx1): s2[idx]
template <int AMODE, int EPI>
__global__ __launch_bounds__(256) void gemm_kernel(
    const float* __restrict__ A,
    const float* __restrict__ u2s, const float* __restrict__ usr,
    const float* __restrict__ srv,
    const float* __restrict__ W, const float* __restrict__ bias,
    float* __restrict__ Cout,
    const int* __restrict__ idx0, const int* __restrict__ idx1,
    float* __restrict__ s01, float* __restrict__ s2,
    int M, int N, int K)
{
    __shared__ float As[BK][BM + 4];  // k-major so compute reads are float4
    __shared__ float Bs[BK][BN + 4];

    const int tid = threadIdx.x;
    const int tx = tid & 15;   // 0..15 -> N
    const int ty = tid >> 4;   // 0..15 -> M
    const int m0 = blockIdx.y * BM;
    const int n0 = blockIdx.x * BN;

    // A loader: thread -> (row, 4 consecutive k)
    const int a_row = tid >> 2;        // 0..63
    const int a_col = (tid & 3) * 4;   // 0,4,8,12
    // B loader: thread -> (k row, 4 consecutive n)
    const int b_row = tid >> 4;        // 0..15
    const int b_col = (tid & 15) * 4;  // 0..60

    float acc[4][4] = {{0.f}};

    for (int k0 = 0; k0 < K; k0 += BK) {
        // ---- stage A tile ----
        if (AMODE == A_PLAIN) {
            const float4 v = *reinterpret_cast<const float4*>(
                &A[(size_t)(m0 + a_row) * K + k0 + a_col]);
            As[a_col + 0][a_row] = v.x;
            As[a_col + 1][a_row] = v.y;
            As[a_col + 2][a_row] = v.z;
            As[a_col + 3][a_row] = v.w;
        } else {
            const int row = m0 + a_row;
#pragma unroll
            for (int i = 0; i < 4; ++i) {
                const int k = k0 + a_col + i;
                float v = 0.f;
                if (k < OUT_DIM)           v = u2s[(size_t)row * OUT_DIM + k];
                else if (k < OUT_DIM + NU) v = usr[(size_t)row * NU + (k - OUT_DIM)];
                else if (k < IN_DIM)       v = srv[(size_t)row * NS + (k - OUT_DIM - NU)];
                As[a_col + i][a_row] = v;
            }
        }
        // ---- stage B tile (W is K x N row-major) ----
        {
            const int k = k0 + b_row;
            float4 v = make_float4(0.f, 0.f, 0.f, 0.f);
            if (k < K)
                v = *reinterpret_cast<const float4*>(&W[(size_t)k * N + n0 + b_col]);
            Bs[b_row][b_col + 0] = v.x;
            Bs[b_row][b_col + 1] = v.y;
            Bs[b_row][b_col + 2] = v.z;
            Bs[b_row][b_col + 3] = v.w;
        }
        __syncthreads();

#pragma unroll
        for (int kk = 0; kk < BK; ++kk) {
            const float4 av = *reinterpret_cast<const float4*>(&As[kk][ty * 4]);
            const float4 bv = *reinterpret_cast<const float4*>(&Bs[kk][tx * 4]);
            const float a[4] = {av.x, av.y, av.z, av.w};
            const float b[4] = {bv.x, bv.y, bv.z, bv.w};
#pragma unroll
            for (int i = 0; i < 4; ++i)
#pragma unroll
                for (int j = 0; j < 4; ++j)
                    acc[i][j] = fmaf(a[i], b[j], acc[i][j]);
        }
        __syncthreads();
    }

    // ---- epilogue ----
    if (EPI == EPI_RELU) {
#pragma unroll
        for (int i = 0; i < 4; ++i) {
            const int row = m0 + ty * 4 + i;
#pragma unroll
            for (int j = 0; j < 4; ++j) {
                const int col = n0 + tx * 4 + j;
                Cout[(size_t)row * N + col] = fmaxf(acc[i][j] + bias[col], 0.f);
            }
        }
    } else {
        // whole block lives in one section (BN=64 divides 1024, n0 aligned)
        const int sec = n0 >> 10;               // uniform over block
        const int wbase = (n0 & 1023) + tx * 4; // within-section column
        const int* __restrict__ idxs = (sec < 2) ? idx0 : idx1;
#pragma unroll
        for (int i = 0; i < 4; ++i) {
            const int row = m0 + ty * 4 + i;
            const int4 iv = *reinterpret_cast<const int4*>(
                &idxs[(size_t)row * OUT_DIM + wbase]);
            const int idx[4] = {iv.x, iv.y, iv.z, iv.w};
#pragma unroll
            for (int j = 0; j < 4; ++j) {
                const int col = n0 + tx * 4 + j;
                const float e = __expf(acc[i][j] + bias[col]);
                Cout[(size_t)sec * EDGES + (size_t)row * OUT_DIM + wbase + j] = e;
                if (sec < 2)
                    atomicAdd(&s01[2 * idx[j] + sec], e);
                else
                    atomicAdd(&s2[idx[j]], e);
            }
        }
    }
}

// ---------------- softmax finish -------------------------------------------
__global__ __launch_bounds__(256) void init_s_kernel(float* __restrict__ s01,
                                                     float* __restrict__ s2) {
    const int i = blockIdx.x * blockDim.x + threadIdx.x;
    if (i < 2 * NSEG) s01[i] = 0.f;
    if (i < NSEG) s2[i] = 0.f;
}

__global__ __launch_bounds__(256) void recip_kernel(float* __restrict__ s01,
                                                    float* __restrict__ s2) {
    const int i = blockIdx.x * blockDim.x + threadIdx.x;
    if (i < 2 * NSEG) s01[i] = 1.f / s01[i];
    if (i < NSEG) s2[i] = 1.f / s2[i];
}

__global__ __launch_bounds__(256) void segdiv_kernel(
    float* __restrict__ vals, const int* __restrict__ idx0,
    const int* __restrict__ idx1, const float* __restrict__ r01,
    const float* __restrict__ r2) {
    const int w = blockIdx.x * blockDim.x + threadIdx.x;
    if (w >= EDGES) return;
    const int i0 = idx0[w];
    const int i2 = idx1[w];
    const float r0 = r01[2 * i0];      // same line as r1
    const float r1 = r01[2 * i0 + 1];
    const float rc = r2[i2];
    vals[w] *= r0;
    vals[EDGES + w] *= r1;
    vals[2 * EDGES + w] *= rc;
}

// ---------------------------------------------------------------------------
extern "C" void kernel_launch(void* const* d_in, const int* in_sizes, int n_in,
                              void* d_out, int out_size, void* d_ws,
                              size_t ws_size, hipStream_t stream) {
    const float* u2s = (const float*)d_in[0];
    const float* usr = (const float*)d_in[1];
    const float* srv = (const float*)d_in[2];
    const int* edge = (const int*)d_in[3];
    const float* W1 = (const float*)d_in[4];
    const float* b1 = (const float*)d_in[5];
    const float* W2 = (const float*)d_in[6];
    const float* b2 = (const float*)d_in[7];
    const float* W3 = (const float*)d_in[8];
    const float* b3 = (const float*)d_in[9];
    const float* W4 = (const float*)d_in[10];
    const float* b4 = (const float*)d_in[11];

    const int* idx0 = edge;
    const int* idx1 = edge + EDGES;

    // workspace: h1,h2,h3 (2M floats each) | s01 (2M) | s2 (1M)  = 36 MB
    float* h1 = (float*)d_ws;
    float* h2 = h1 + (size_t)B_GRAPHS * HID;
    float* h3 = h2 + (size_t)B_GRAPHS * HID;
    float* s01 = h3 + (size_t)B_GRAPHS * HID;
    float* s2 = s01 + 2 * (size_t)NSEG;
    float* outp = (float*)d_out;

    const dim3 blk(256);

    init_s_kernel<<<(2 * NSEG + 255) / 256, blk, 0, stream>>>(s01, s2);

    // GEMM1: feats(8192x1160) @ W1(1160x256) -> relu -> h1
    gemm_kernel<A_FEATS, EPI_RELU>
        <<<dim3(HID / BN, B_GRAPHS / BM), blk, 0, stream>>>(
            nullptr, u2s, usr, srv, W1, b1, h1, nullptr, nullptr, nullptr,
            nullptr, B_GRAPHS, HID, IN_DIM);
    // GEMM2: h1 @ W2 -> relu -> h2
    gemm_kernel<A_PLAIN, EPI_RELU>
        <<<dim3(HID / BN, B_GRAPHS / BM), blk, 0, stream>>>(
            h1, nullptr, nullptr, nullptr, W2, b2, h2, nullptr, nullptr,
            nullptr, nullptr, B_GRAPHS, HID, HID);
    // GEMM3: h2 @ W3 -> relu -> h3
    gemm_kernel<A_PLAIN, EPI_RELU>
        <<<dim3(HID / BN, B_GRAPHS / BM), blk, 0, stream>>>(
            h2, nullptr, nullptr, nullptr, W3, b3, h3, nullptr, nullptr,
            nullptr, nullptr, B_GRAPHS, HID, HID);
    // GEMM4 fused: h3 @ W4 + b4 -> exp -> d_out (3 sections) + segment sums
    gemm_kernel<A_PLAIN, EPI_SCHES>
        <<<dim3(3 * OUT_DIM / BN, B_GRAPHS / BM), blk, 0, stream>>>(
            h3, nullptr, nullptr, nullptr, W4, b4, outp, idx0, idx1, s01, s2,
            B_GRAPHS, 3 * OUT_DIM, HID);

    recip_kernel<<<(2 * NSEG + 255) / 256, blk, 0, stream>>>(s01, s2);
    segdiv_kernel<<<(EDGES + 255) / 256, blk, 0, stream>>>(outp, idx0, idx1,
                                                           s01, s2);
}

// Round 3
// 1187.340 us; speedup vs baseline: 2.2385x; 1.3990x over previous
//
#include <hip/hip_runtime.h>
#include <math.h>

#define B_GRAPHS 8192
#define OUT_DIM 1024
#define NU 128
#define NS 8
#define IN_DIM 1160          // OUT_DIM + NU + NS
#define HID 256
#define NSEG (B_GRAPHS * NU)        // 1048576 = 2^20
#define EDGES (B_GRAPHS * OUT_DIM)  // 8388608 = 2^23

#define FIX_SCALE 8388608.0f        // 2^23 fixed-point scale for packed sums
#define FIX_INV (1.0f / 8388608.0f)

// ---------------- tiled fp32 GEMM: C = relu(A @ W + bias) ------------------
// BM=BN=64, BK=16, 256 threads, 4x4 micro-tile per thread.
#define BM 64
#define BN 64
#define BK 16

enum { A_PLAIN = 0, A_FEATS = 1 };

template <int AMODE>
__global__ __launch_bounds__(256) void gemm_relu_kernel(
    const float* __restrict__ A,
    const float* __restrict__ u2s, const float* __restrict__ usr,
    const float* __restrict__ srv,
    const float* __restrict__ W, const float* __restrict__ bias,
    float* __restrict__ Cout, int M, int N, int K)
{
    __shared__ float As[BK][BM + 4];  // k-major so compute reads are float4
    __shared__ float Bs[BK][BN + 4];

    const int tid = threadIdx.x;
    const int tx = tid & 15;   // 0..15 -> N
    const int ty = tid >> 4;   // 0..15 -> M
    const int m0 = blockIdx.y * BM;
    const int n0 = blockIdx.x * BN;

    const int a_row = tid >> 2;        // 0..63
    const int a_col = (tid & 3) * 4;   // 0,4,8,12
    const int b_row = tid >> 4;        // 0..15
    const int b_col = (tid & 15) * 4;  // 0..60

    float acc[4][4] = {{0.f}};

    for (int k0 = 0; k0 < K; k0 += BK) {
        // ---- stage A tile ----
        if (AMODE == A_PLAIN) {
            const float4 v = *reinterpret_cast<const float4*>(
                &A[(size_t)(m0 + a_row) * K + k0 + a_col]);
            As[a_col + 0][a_row] = v.x;
            As[a_col + 1][a_row] = v.y;
            As[a_col + 2][a_row] = v.z;
            As[a_col + 3][a_row] = v.w;
        } else {
            // feats concat loader; all segment boundaries (1024,1152,1160)
            // are multiples of 4, so each quad lives in one source.
            const int row = m0 + a_row;
            const int k = k0 + a_col;
            float4 v = make_float4(0.f, 0.f, 0.f, 0.f);
            if (k < OUT_DIM)
                v = *reinterpret_cast<const float4*>(&u2s[(size_t)row * OUT_DIM + k]);
            else if (k < OUT_DIM + NU)
                v = *reinterpret_cast<const float4*>(&usr[(size_t)row * NU + (k - OUT_DIM)]);
            else if (k < IN_DIM)
                v = *reinterpret_cast<const float4*>(&srv[(size_t)row * NS + (k - OUT_DIM - NU)]);
            As[a_col + 0][a_row] = v.x;
            As[a_col + 1][a_row] = v.y;
            As[a_col + 2][a_row] = v.z;
            As[a_col + 3][a_row] = v.w;
        }
        // ---- stage B tile (W is K x N row-major) ----
        {
            const int k = k0 + b_row;
            float4 v = make_float4(0.f, 0.f, 0.f, 0.f);
            if (k < K)
                v = *reinterpret_cast<const float4*>(&W[(size_t)k * N + n0 + b_col]);
            Bs[b_row][b_col + 0] = v.x;
            Bs[b_row][b_col + 1] = v.y;
            Bs[b_row][b_col + 2] = v.z;
            Bs[b_row][b_col + 3] = v.w;
        }
        __syncthreads();

#pragma unroll
        for (int kk = 0; kk < BK; ++kk) {
            const float4 av = *reinterpret_cast<const float4*>(&As[kk][ty * 4]);
            const float4 bv = *reinterpret_cast<const float4*>(&Bs[kk][tx * 4]);
            const float a[4] = {av.x, av.y, av.z, av.w};
            const float b[4] = {bv.x, bv.y, bv.z, bv.w};
#pragma unroll
            for (int i = 0; i < 4; ++i)
#pragma unroll
                for (int j = 0; j < 4; ++j)
                    acc[i][j] = fmaf(a[i], b[j], acc[i][j]);
        }
        __syncthreads();
    }

#pragma unroll
    for (int i = 0; i < 4; ++i) {
        const int row = m0 + ty * 4 + i;
#pragma unroll
        for (int j = 0; j < 4; ++j) {
            const int col = n0 + tx * 4 + j;
            Cout[(size_t)row * N + col] = fmaxf(acc[i][j] + bias[col], 0.f);
        }
    }
}

// ---------------- GEMM4 tri-panel fused: sches -> exp -> out + seg sums ----
// Grid covers N=1024 within-section cols; each block computes the SAME col
// tile for all three sections (cols w, w+1024, w+2048) so one thread holds
// e0,e1,e2 of an edge. Sections 0,1 share idx0 -> one packed u64 atomic.
__global__ __launch_bounds__(256) void gemm4_fused_kernel(
    const float* __restrict__ A, const float* __restrict__ W,
    const float* __restrict__ bias, float* __restrict__ out,
    const int* __restrict__ idx0, const int* __restrict__ idx1,
    unsigned long long* __restrict__ s01, float* __restrict__ s2)
{
    __shared__ float As[BK][BM + 4];
    __shared__ float Bs[BK][3 * BN + 4];

    const int tid = threadIdx.x;
    const int tx = tid & 15;
    const int ty = tid >> 4;
    const int m0 = blockIdx.y * BM;
    const int n0 = blockIdx.x * BN;   // within-section col base, 0..960

    const int a_row = tid >> 2;
    const int a_col = (tid & 3) * 4;
    const int b_row = tid >> 4;
    const int b_col = (tid & 15) * 4;

    float acc[3][4][4] = {{{0.f}}};

    for (int k0 = 0; k0 < HID; k0 += BK) {
        {
            const float4 v = *reinterpret_cast<const float4*>(
                &A[(size_t)(m0 + a_row) * HID + k0 + a_col]);
            As[a_col + 0][a_row] = v.x;
            As[a_col + 1][a_row] = v.y;
            As[a_col + 2][a_row] = v.z;
            As[a_col + 3][a_row] = v.w;
        }
        {
            const int k = k0 + b_row;
#pragma unroll
            for (int p = 0; p < 3; ++p) {
                const float4 v = *reinterpret_cast<const float4*>(
                    &W[(size_t)k * (3 * OUT_DIM) + p * OUT_DIM + n0 + b_col]);
                Bs[b_row][p * BN + b_col + 0] = v.x;
                Bs[b_row][p * BN + b_col + 1] = v.y;
                Bs[b_row][p * BN + b_col + 2] = v.z;
                Bs[b_row][p * BN + b_col + 3] = v.w;
            }
        }
        __syncthreads();

#pragma unroll
        for (int kk = 0; kk < BK; ++kk) {
            const float4 av = *reinterpret_cast<const float4*>(&As[kk][ty * 4]);
            const float a[4] = {av.x, av.y, av.z, av.w};
#pragma unroll
            for (int p = 0; p < 3; ++p) {
                const float4 bv =
                    *reinterpret_cast<const float4*>(&Bs[kk][p * BN + tx * 4]);
                const float b[4] = {bv.x, bv.y, bv.z, bv.w};
#pragma unroll
                for (int i = 0; i < 4; ++i)
#pragma unroll
                    for (int j = 0; j < 4; ++j)
                        acc[p][i][j] = fmaf(a[i], b[j], acc[p][i][j]);
            }
        }
        __syncthreads();
    }

    // ---- epilogue: exp, store, packed segment-sum atomics ----
    const int wbase = n0 + tx * 4;
#pragma unroll
    for (int i = 0; i < 4; ++i) {
        const int row = m0 + ty * 4 + i;
        const int4 iv0 = *reinterpret_cast<const int4*>(
            &idx0[(size_t)row * OUT_DIM + wbase]);
        const int4 iv1 = *reinterpret_cast<const int4*>(
            &idx1[(size_t)row * OUT_DIM + wbase]);
        const int i0[4] = {iv0.x, iv0.y, iv0.z, iv0.w};
        const int i1[4] = {iv1.x, iv1.y, iv1.z, iv1.w};
#pragma unroll
        for (int j = 0; j < 4; ++j) {
            const int w = wbase + j;
            const float e0 = __expf(acc[0][i][j] + bias[w]);
            const float e1 = __expf(acc[1][i][j] + bias[OUT_DIM + w]);
            const float e2 = __expf(acc[2][i][j] + bias[2 * OUT_DIM + w]);
            out[(size_t)0 * EDGES + (size_t)row * OUT_DIM + w] = e0;
            out[(size_t)1 * EDGES + (size_t)row * OUT_DIM + w] = e1;
            out[(size_t)2 * EDGES + (size_t)row * OUT_DIM + w] = e2;
            const unsigned q0 = (unsigned)__float2uint_rn(e0 * FIX_SCALE);
            const unsigned q1 = (unsigned)__float2uint_rn(e1 * FIX_SCALE);
            const unsigned long long packed =
                ((unsigned long long)q0 << 32) | (unsigned long long)q1;
            atomicAdd(&s01[i0[j]], packed);
            atomicAdd(&s2[i1[j]], e2);
        }
    }
}

// ---------------- softmax finish -------------------------------------------
__global__ __launch_bounds__(256) void recip_kernel(
    unsigned long long* __restrict__ s01, float* __restrict__ s2) {
    const int i = blockIdx.x * blockDim.x + threadIdx.x;
    if (i >= NSEG) return;
    const unsigned long long v = s01[i];
    const float sum0 = (float)(unsigned)(v >> 32) * FIX_INV;
    const float sum1 = (float)(unsigned)(v & 0xffffffffu) * FIX_INV;
    float2 r;
    r.x = 1.f / sum0;
    r.y = 1.f / sum1;
    reinterpret_cast<float2*>(s01)[i] = r;  // overwrite in place as (r0, r1)
    s2[i] = 1.f / s2[i];
}

__global__ __launch_bounds__(256) void segdiv_kernel(
    float* __restrict__ vals, const int* __restrict__ idx0,
    const int* __restrict__ idx1, const float* __restrict__ r01,
    const float* __restrict__ r2) {
    const int w = blockIdx.x * blockDim.x + threadIdx.x;
    if (w >= EDGES) return;
    const int i0 = idx0[w];
    const int i2 = idx1[w];
    const float2 rv = reinterpret_cast<const float2*>(r01)[i0];
    const float rc = r2[i2];
    vals[w] *= rv.x;
    vals[EDGES + w] *= rv.y;
    vals[2 * EDGES + w] *= rc;
}

// ---------------------------------------------------------------------------
extern "C" void kernel_launch(void* const* d_in, const int* in_sizes, int n_in,
                              void* d_out, int out_size, void* d_ws,
                              size_t ws_size, hipStream_t stream) {
    const float* u2s = (const float*)d_in[0];
    const float* usr = (const float*)d_in[1];
    const float* srv = (const float*)d_in[2];
    const int* edge = (const int*)d_in[3];
    const float* W1 = (const float*)d_in[4];
    const float* b1 = (const float*)d_in[5];
    const float* W2 = (const float*)d_in[6];
    const float* b2 = (const float*)d_in[7];
    const float* W3 = (const float*)d_in[8];
    const float* b3 = (const float*)d_in[9];
    const float* W4 = (const float*)d_in[10];
    const float* b4 = (const float*)d_in[11];

    const int* idx0 = edge;
    const int* idx1 = edge + EDGES;

    // workspace: h1,h2,h3 (8 MB each) | s01 u64[NSEG] (8 MB) | s2 f32[NSEG] (4 MB)
    float* h1 = (float*)d_ws;
    float* h2 = h1 + (size_t)B_GRAPHS * HID;
    float* h3 = h2 + (size_t)B_GRAPHS * HID;
    unsigned long long* s01 = (unsigned long long*)(h3 + (size_t)B_GRAPHS * HID);
    float* s2 = (float*)(s01 + (size_t)NSEG);
    float* outp = (float*)d_out;

    const dim3 blk(256);

    // zero s01 + s2 (contiguous, 12 MB)
    hipMemsetAsync(s01, 0, (size_t)NSEG * 8 + (size_t)NSEG * 4, stream);

    // GEMM1: feats(8192x1160) @ W1 -> relu -> h1
    gemm_relu_kernel<A_FEATS>
        <<<dim3(HID / BN, B_GRAPHS / BM), blk, 0, stream>>>(
            nullptr, u2s, usr, srv, W1, b1, h1, B_GRAPHS, HID, IN_DIM);
    // GEMM2: h1 @ W2 -> relu -> h2
    gemm_relu_kernel<A_PLAIN>
        <<<dim3(HID / BN, B_GRAPHS / BM), blk, 0, stream>>>(
            h1, nullptr, nullptr, nullptr, W2, b2, h2, B_GRAPHS, HID, HID);
    // GEMM3: h2 @ W3 -> relu -> h3
    gemm_relu_kernel<A_PLAIN>
        <<<dim3(HID / BN, B_GRAPHS / BM), blk, 0, stream>>>(
            h2, nullptr, nullptr, nullptr, W3, b3, h3, B_GRAPHS, HID, HID);
    // GEMM4 tri-panel fused: exp + out + packed segment sums
    gemm4_fused_kernel<<<dim3(OUT_DIM / BN, B_GRAPHS / BM), blk, 0, stream>>>(
        h3, W4, b4, outp, idx0, idx1, s01, s2);

    recip_kernel<<<(NSEG + 255) / 256, blk, 0, stream>>>(s01, s2);
    segdiv_kernel<<<(EDGES + 255) / 256, blk, 0, stream>>>(outp, idx0, idx1,
                                                           (const float*)s01, s2);
}

// Round 4
// 1040.672 us; speedup vs baseline: 2.5539x; 1.1409x over previous
//
#include <hip/hip_runtime.h>
#include <math.h>

#define B_GRAPHS 8192
#define OUT_DIM 1024
#define NU 128
#define NS 8
#define IN_DIM 1160          // OUT_DIM + NU + NS
#define HID 256
#define NSEG (B_GRAPHS * NU)        // 1048576 = 2^20
#define EDGES (B_GRAPHS * OUT_DIM)  // 8388608 = 2^23

// ---- binning parameters ----
#define BINS 2048
#define SEGS_PER_BIN 512            // NSEG / BINS
#define BIN_CAP 2880                // >= mean(2048) + 18 sigma for a half
#define HALF (EDGES / 2)            // 4194304
#define CHUNK 16384                 // edges per hist/scatter block
#define HIST_BLOCKS (HALF / CHUNK)  // 256

// ---------------- tiled fp32 GEMM: C = relu(A @ W + bias) ------------------
#define BM 64
#define BN 64
#define BK 16

enum { A_PLAIN = 0, A_FEATS = 1 };

template <int AMODE>
__global__ __launch_bounds__(256) void gemm_relu_kernel(
    const float* __restrict__ A,
    const float* __restrict__ u2s, const float* __restrict__ usr,
    const float* __restrict__ srv,
    const float* __restrict__ W, const float* __restrict__ bias,
    float* __restrict__ Cout, int M, int N, int K)
{
    __shared__ float As[BK][BM + 4];  // k-major so compute reads are float4
    __shared__ float Bs[BK][BN + 4];

    const int tid = threadIdx.x;
    const int tx = tid & 15;
    const int ty = tid >> 4;
    const int m0 = blockIdx.y * BM;
    const int n0 = blockIdx.x * BN;

    const int a_row = tid >> 2;
    const int a_col = (tid & 3) * 4;
    const int b_row = tid >> 4;
    const int b_col = (tid & 15) * 4;

    float acc[4][4] = {{0.f}};

    for (int k0 = 0; k0 < K; k0 += BK) {
        if (AMODE == A_PLAIN) {
            const float4 v = *reinterpret_cast<const float4*>(
                &A[(size_t)(m0 + a_row) * K + k0 + a_col]);
            As[a_col + 0][a_row] = v.x;
            As[a_col + 1][a_row] = v.y;
            As[a_col + 2][a_row] = v.z;
            As[a_col + 3][a_row] = v.w;
        } else {
            // feats concat; boundaries (1024,1152,1160) are multiples of 4.
            const int row = m0 + a_row;
            const int k = k0 + a_col;
            float4 v = make_float4(0.f, 0.f, 0.f, 0.f);
            if (k < OUT_DIM)
                v = *reinterpret_cast<const float4*>(&u2s[(size_t)row * OUT_DIM + k]);
            else if (k < OUT_DIM + NU)
                v = *reinterpret_cast<const float4*>(&usr[(size_t)row * NU + (k - OUT_DIM)]);
            else if (k < IN_DIM)
                v = *reinterpret_cast<const float4*>(&srv[(size_t)row * NS + (k - OUT_DIM - NU)]);
            As[a_col + 0][a_row] = v.x;
            As[a_col + 1][a_row] = v.y;
            As[a_col + 2][a_row] = v.z;
            As[a_col + 3][a_row] = v.w;
        }
        {
            const int k = k0 + b_row;
            float4 v = make_float4(0.f, 0.f, 0.f, 0.f);
            if (k < K)
                v = *reinterpret_cast<const float4*>(&W[(size_t)k * N + n0 + b_col]);
            Bs[b_row][b_col + 0] = v.x;
            Bs[b_row][b_col + 1] = v.y;
            Bs[b_row][b_col + 2] = v.z;
            Bs[b_row][b_col + 3] = v.w;
        }
        __syncthreads();

#pragma unroll
        for (int kk = 0; kk < BK; ++kk) {
            const float4 av = *reinterpret_cast<const float4*>(&As[kk][ty * 4]);
            const float4 bv = *reinterpret_cast<const float4*>(&Bs[kk][tx * 4]);
            const float a[4] = {av.x, av.y, av.z, av.w};
            const float b[4] = {bv.x, bv.y, bv.z, bv.w};
#pragma unroll
            for (int i = 0; i < 4; ++i)
#pragma unroll
                for (int j = 0; j < 4; ++j)
                    acc[i][j] = fmaf(a[i], b[j], acc[i][j]);
        }
        __syncthreads();
    }

#pragma unroll
    for (int i = 0; i < 4; ++i) {
        const int row = m0 + ty * 4 + i;
#pragma unroll
        for (int j = 0; j < 4; ++j) {
            const int col = n0 + tx * 4 + j;
            Cout[(size_t)row * N + col] = fmaxf(acc[i][j] + bias[col], 0.f);
        }
    }
}

// ---------------- GEMM4 tri-panel: sches -> exp -> out (atomic-free) -------
__global__ __launch_bounds__(256) void gemm4_kernel(
    const float* __restrict__ A, const float* __restrict__ W,
    const float* __restrict__ bias, float* __restrict__ out)
{
    __shared__ float As[BK][BM + 4];
    __shared__ float Bs[BK][3 * BN + 4];

    const int tid = threadIdx.x;
    const int tx = tid & 15;
    const int ty = tid >> 4;
    const int m0 = blockIdx.y * BM;
    const int n0 = blockIdx.x * BN;   // within-section col base

    const int a_row = tid >> 2;
    const int a_col = (tid & 3) * 4;
    const int b_row = tid >> 4;
    const int b_col = (tid & 15) * 4;

    float acc[3][4][4] = {{{0.f}}};

    for (int k0 = 0; k0 < HID; k0 += BK) {
        {
            const float4 v = *reinterpret_cast<const float4*>(
                &A[(size_t)(m0 + a_row) * HID + k0 + a_col]);
            As[a_col + 0][a_row] = v.x;
            As[a_col + 1][a_row] = v.y;
            As[a_col + 2][a_row] = v.z;
            As[a_col + 3][a_row] = v.w;
        }
        {
            const int k = k0 + b_row;
#pragma unroll
            for (int p = 0; p < 3; ++p) {
                const float4 v = *reinterpret_cast<const float4*>(
                    &W[(size_t)k * (3 * OUT_DIM) + p * OUT_DIM + n0 + b_col]);
                Bs[b_row][p * BN + b_col + 0] = v.x;
                Bs[b_row][p * BN + b_col + 1] = v.y;
                Bs[b_row][p * BN + b_col + 2] = v.z;
                Bs[b_row][p * BN + b_col + 3] = v.w;
            }
        }
        __syncthreads();

#pragma unroll
        for (int kk = 0; kk < BK; ++kk) {
            const float4 av = *reinterpret_cast<const float4*>(&As[kk][ty * 4]);
            const float a[4] = {av.x, av.y, av.z, av.w};
#pragma unroll
            for (int p = 0; p < 3; ++p) {
                const float4 bv =
                    *reinterpret_cast<const float4*>(&Bs[kk][p * BN + tx * 4]);
                const float b[4] = {bv.x, bv.y, bv.z, bv.w};
#pragma unroll
                for (int i = 0; i < 4; ++i)
#pragma unroll
                    for (int j = 0; j < 4; ++j)
                        acc[p][i][j] = fmaf(a[i], b[j], acc[p][i][j]);
            }
        }
        __syncthreads();
    }

    const int wbase = n0 + tx * 4;
    float4 bv[3];
#pragma unroll
    for (int p = 0; p < 3; ++p)
        bv[p] = *reinterpret_cast<const float4*>(&bias[p * OUT_DIM + wbase]);
#pragma unroll
    for (int i = 0; i < 4; ++i) {
        const int row = m0 + ty * 4 + i;
#pragma unroll
        for (int p = 0; p < 3; ++p) {
            float4 ev;
            ev.x = __expf(acc[p][i][0] + bv[p].x);
            ev.y = __expf(acc[p][i][1] + bv[p].y);
            ev.z = __expf(acc[p][i][2] + bv[p].z);
            ev.w = __expf(acc[p][i][3] + bv[p].w);
            *reinterpret_cast<float4*>(
                &out[(size_t)p * EDGES + (size_t)row * OUT_DIM + wbase]) = ev;
        }
    }
}

// ---------------- binning: histogram + scatter of packed records -----------
// record u32 = (seg & 511) << 23 | w   (w < 2^23, seg_low 9 bits, bin = seg>>9)
__global__ __launch_bounds__(256) void hist_scatter_kernel(
    const int* __restrict__ idx, int w0, unsigned* __restrict__ P,
    unsigned* __restrict__ cursor)
{
    __shared__ unsigned hist[BINS];   // counts, then bases after reservation
    __shared__ unsigned offs[BINS];
    const int tid = threadIdx.x;
    const int base = w0 + blockIdx.x * CHUNK;

    for (int b = tid; b < BINS; b += 256) { hist[b] = 0; offs[b] = 0; }
    __syncthreads();

#pragma unroll 4
    for (int i = 0; i < CHUNK / 256; ++i) {
        const int seg = idx[base + i * 256 + tid];
        atomicAdd(&hist[seg >> 9], 1u);
    }
    __syncthreads();

    for (int b = tid; b < BINS; b += 256)
        hist[b] = atomicAdd(&cursor[b], hist[b]);  // reserve; hist := base
    __syncthreads();

#pragma unroll 4
    for (int i = 0; i < CHUNK / 256; ++i) {
        const int w = base + i * 256 + tid;
        const int seg = idx[w];
        const int b = seg >> 9;
        const unsigned o = atomicAdd(&offs[b], 1u);
        P[(size_t)b * BIN_CAP + hist[b] + o] =
            ((unsigned)(seg & 511) << 23) | (unsigned)w;
    }
}

// ---------------- per-bin reduce: exclusive owner, LDS sub-table -----------
__global__ __launch_bounds__(256) void reduce01_kernel(
    const unsigned* __restrict__ P, const unsigned* __restrict__ cursor,
    const float* __restrict__ out, float2* __restrict__ s01, int accum)
{
    __shared__ float sub0[SEGS_PER_BIN];
    __shared__ float sub1[SEGS_PER_BIN];
    const int b = blockIdx.x;
    const int tid = threadIdx.x;
    for (int i = tid; i < SEGS_PER_BIN; i += 256) { sub0[i] = 0.f; sub1[i] = 0.f; }
    __syncthreads();

    const int cnt = (int)cursor[b];
    const unsigned* rec = &P[(size_t)b * BIN_CAP];
    for (int i = tid; i < cnt; i += 256) {
        const unsigned r = rec[i];
        const int w = r & 0x7FFFFF;
        const int sl = r >> 23;
        atomicAdd(&sub0[sl], out[w]);
        atomicAdd(&sub1[sl], out[EDGES + w]);
    }
    __syncthreads();

    for (int i = tid; i < SEGS_PER_BIN; i += 256) {
        const int seg = b * SEGS_PER_BIN + i;
        float2 v = make_float2(sub0[i], sub1[i]);
        if (accum) { const float2 p = s01[seg]; v.x += p.x; v.y += p.y; }
        s01[seg] = v;
    }
}

__global__ __launch_bounds__(256) void reduce2_kernel(
    const unsigned* __restrict__ P, const unsigned* __restrict__ cursor,
    const float* __restrict__ out, float* __restrict__ s2, int accum)
{
    __shared__ float sub[SEGS_PER_BIN];
    const int b = blockIdx.x;
    const int tid = threadIdx.x;
    for (int i = tid; i < SEGS_PER_BIN; i += 256) sub[i] = 0.f;
    __syncthreads();

    const int cnt = (int)cursor[b];
    const unsigned* rec = &P[(size_t)b * BIN_CAP];
    for (int i = tid; i < cnt; i += 256) {
        const unsigned r = rec[i];
        const int w = r & 0x7FFFFF;
        const int sl = r >> 23;
        atomicAdd(&sub[sl], out[2 * (size_t)EDGES + w]);
    }
    __syncthreads();

    for (int i = tid; i < SEGS_PER_BIN; i += 256) {
        const int seg = b * SEGS_PER_BIN + i;
        float v = sub[i];
        if (accum) v += s2[seg];
        s2[seg] = v;
    }
}

// ---------------- softmax finish -------------------------------------------
__global__ __launch_bounds__(256) void recip_kernel(float2* __restrict__ s01,
                                                    float* __restrict__ s2) {
    const int i = blockIdx.x * blockDim.x + threadIdx.x;
    if (i >= NSEG) return;
    const float2 v = s01[i];
    s01[i] = make_float2(1.f / v.x, 1.f / v.y);
    s2[i] = 1.f / s2[i];
}

__global__ __launch_bounds__(256) void segdiv_kernel(
    float* __restrict__ vals, const int* __restrict__ idx0,
    const int* __restrict__ idx1, const float2* __restrict__ r01,
    const float* __restrict__ r2) {
    const int w = blockIdx.x * blockDim.x + threadIdx.x;
    if (w >= EDGES) return;
    const float2 rv = r01[idx0[w]];
    const float rc = r2[idx1[w]];
    vals[w] *= rv.x;
    vals[EDGES + w] *= rv.y;
    vals[2 * (size_t)EDGES + w] *= rc;
}

// ---------------------------------------------------------------------------
extern "C" void kernel_launch(void* const* d_in, const int* in_sizes, int n_in,
                              void* d_out, int out_size, void* d_ws,
                              size_t ws_size, hipStream_t stream) {
    const float* u2s = (const float*)d_in[0];
    const float* usr = (const float*)d_in[1];
    const float* srv = (const float*)d_in[2];
    const int* edge = (const int*)d_in[3];
    const float* W1 = (const float*)d_in[4];
    const float* b1 = (const float*)d_in[5];
    const float* W2 = (const float*)d_in[6];
    const float* b2 = (const float*)d_in[7];
    const float* W3 = (const float*)d_in[8];
    const float* b3 = (const float*)d_in[9];
    const float* W4 = (const float*)d_in[10];
    const float* b4 = (const float*)d_in[11];

    const int* idx0 = edge;
    const int* idx1 = edge + EDGES;

    // ws layout:
    //   [0,24MB):  h1,h2,h3 (8MB each) -- later aliased by P + cursor
    //   [24,32MB): s01 float2[NSEG]
    //   [32,36MB): s2 float[NSEG]
    char* ws = (char*)d_ws;
    float* h1 = (float*)ws;
    float* h2 = h1 + (size_t)B_GRAPHS * HID;
    float* h3 = h2 + (size_t)B_GRAPHS * HID;
    unsigned* P = (unsigned*)ws;                       // aliases h1..h3
    unsigned* cursor = P + (size_t)BINS * BIN_CAP;     // 23.6MB offset, 8KB
    float2* s01 = (float2*)(ws + 24u * 1024 * 1024);
    float* s2 = (float*)(ws + 32u * 1024 * 1024);
    float* outp = (float*)d_out;

    const dim3 blk(256);

    // ---- MLP ----
    gemm_relu_kernel<A_FEATS>
        <<<dim3(HID / BN, B_GRAPHS / BM), blk, 0, stream>>>(
            nullptr, u2s, usr, srv, W1, b1, h1, B_GRAPHS, HID, IN_DIM);
    gemm_relu_kernel<A_PLAIN>
        <<<dim3(HID / BN, B_GRAPHS / BM), blk, 0, stream>>>(
            h1, nullptr, nullptr, nullptr, W2, b2, h2, B_GRAPHS, HID, HID);
    gemm_relu_kernel<A_PLAIN>
        <<<dim3(HID / BN, B_GRAPHS / BM), blk, 0, stream>>>(
            h2, nullptr, nullptr, nullptr, W3, b3, h3, B_GRAPHS, HID, HID);
    gemm4_kernel<<<dim3(OUT_DIM / BN, B_GRAPHS / BM), blk, 0, stream>>>(
        h3, W4, b4, outp);

    // ---- segment sums via bin-scatter-reduce (no device atomics on tables)
    // idx0 (sections 0,1), two halves
    for (int h = 0; h < 2; ++h) {
        hipMemsetAsync(cursor, 0, BINS * sizeof(unsigned), stream);
        hist_scatter_kernel<<<HIST_BLOCKS, blk, 0, stream>>>(idx0, h * HALF, P,
                                                             cursor);
        reduce01_kernel<<<BINS, blk, 0, stream>>>(P, cursor, outp, s01, h);
    }
    // idx1 (section 2), two halves
    for (int h = 0; h < 2; ++h) {
        hipMemsetAsync(cursor, 0, BINS * sizeof(unsigned), stream);
        hist_scatter_kernel<<<HIST_BLOCKS, blk, 0, stream>>>(idx1, h * HALF, P,
                                                             cursor);
        reduce2_kernel<<<BINS, blk, 0, stream>>>(P, cursor, outp, s2, h);
    }

    recip_kernel<<<(NSEG + 255) / 256, blk, 0, stream>>>(s01, s2);
    segdiv_kernel<<<(EDGES + 255) / 256, blk, 0, stream>>>(outp, idx0, idx1,
                                                           s01, s2);
}

// Round 5
// 840.397 us; speedup vs baseline: 3.1626x; 1.2383x over previous
//
#include <hip/hip_runtime.h>
#include <math.h>

#define B_GRAPHS 8192
#define OUT_DIM 1024
#define NU 128
#define NS 8
#define IN_DIM 1160          // OUT_DIM + NU + NS
#define KPAD1 1216           // IN_DIM padded to multiple of 64
#define HID 256
#define NSEG (B_GRAPHS * NU)        // 1048576 = 2^20
#define EDGES (B_GRAPHS * OUT_DIM)  // 8388608 = 2^23

// ---- binning parameters (unchanged from r4) ----
#define BINS 2048
#define SEGS_PER_BIN 512
#define BIN_CAP 2880
#define HALF (EDGES / 2)
#define CHUNK 16384
#define HIST_BLOCKS (HALF / CHUNK)

typedef __attribute__((ext_vector_type(8))) short short8;
typedef __attribute__((ext_vector_type(4))) float f32x4;

__device__ __forceinline__ unsigned short f2bf(float f) {
    unsigned u = __float_as_uint(f);
    const unsigned r = (u >> 16) & 1u;
    return (unsigned short)((u + 0x7fffu + r) >> 16);   // RNE
}

// ================= prep: fp32 -> bf16 conversions ==========================
// feats concat -> F[8192][1216] bf16, zero-padded past 1160.
__global__ __launch_bounds__(256) void convert_feats_kernel(
    const float* __restrict__ u2s, const float* __restrict__ usr,
    const float* __restrict__ srv, unsigned short* __restrict__ F)
{
    const int t = blockIdx.x * 256 + threadIdx.x;   // 8192*152 threads
    const int row = t / 152;
    const int g = t - row * 152;
    const int col = g * 8;
    float v[8];
    if (g < 128) {
        const float4 a = *(const float4*)&u2s[(size_t)row * OUT_DIM + col];
        const float4 b = *(const float4*)&u2s[(size_t)row * OUT_DIM + col + 4];
        v[0]=a.x; v[1]=a.y; v[2]=a.z; v[3]=a.w; v[4]=b.x; v[5]=b.y; v[6]=b.z; v[7]=b.w;
    } else if (g < 144) {
        const int c = col - OUT_DIM;
        const float4 a = *(const float4*)&usr[(size_t)row * NU + c];
        const float4 b = *(const float4*)&usr[(size_t)row * NU + c + 4];
        v[0]=a.x; v[1]=a.y; v[2]=a.z; v[3]=a.w; v[4]=b.x; v[5]=b.y; v[6]=b.z; v[7]=b.w;
    } else if (g == 144) {
        const float4 a = *(const float4*)&srv[(size_t)row * NS];
        const float4 b = *(const float4*)&srv[(size_t)row * NS + 4];
        v[0]=a.x; v[1]=a.y; v[2]=a.z; v[3]=a.w; v[4]=b.x; v[5]=b.y; v[6]=b.z; v[7]=b.w;
    } else {
        for (int i = 0; i < 8; ++i) v[i] = 0.f;
    }
    unsigned short o[8];
    for (int i = 0; i < 8; ++i) o[i] = f2bf(v[i]);
    *reinterpret_cast<short8*>(&F[(size_t)row * KPAD1 + col]) =
        *reinterpret_cast<const short8*>(o);
}

// W[K][N] fp32 -> WT[N][Kpad] bf16 (zero-pad k >= K)
__global__ __launch_bounds__(256) void convert_wT_kernel(
    const float* __restrict__ W, unsigned short* __restrict__ WT,
    int K, int N, int Kpad)
{
    const int t = blockIdx.x * 256 + threadIdx.x;
    if (t >= N * Kpad) return;
    const int n = t / Kpad;
    const int k = t - n * Kpad;
    WT[t] = (k < K) ? f2bf(W[(size_t)k * N + n]) : (unsigned short)0;
}

// ================= bf16 MFMA GEMM ==========================================
// C = A[M x K](bf16,row-major) @ BT[N x K](bf16,W^T) + bias
// tile 128(M) x 64(N), BK=64, 4 waves (2x2), 16x16x32 MFMA, acc 4x2 frags.
// LDS tiles [rows][64] bf16 with 16B-chunk XOR swizzle: chunk ^= (row & 7).
// EPI 0: relu -> bf16 out[M][N].  EPI 1: exp -> f32 d_out 3 sections.
template <int EPI>
__global__ __launch_bounds__(256) void gemm_bf16_kernel(
    const unsigned short* __restrict__ A, const unsigned short* __restrict__ BT,
    const float* __restrict__ bias, void* __restrict__ outv, int N, int K)
{
    __shared__ unsigned short As[128 * 64];
    __shared__ unsigned short Bs[64 * 64];

    const int tid = threadIdx.x;
    const int lane = tid & 63;
    const int wid = tid >> 6;            // 0..3
    const int wm = wid >> 1;             // 0..1 -> 64-row half
    const int wn = wid & 1;              // 0..1 -> 32-col half
    const int m0 = blockIdx.y * 128;
    const int n0 = blockIdx.x * 64;

    const int srow = lane >> 3;          // 0..7
    const int schunk = lane & 7;         // 0..7
    const int sswz = schunk ^ srow;      // rows step by 8 -> row&7 == srow

    f32x4 acc[4][2];
#pragma unroll
    for (int i = 0; i < 4; ++i)
#pragma unroll
        for (int j = 0; j < 2; ++j) acc[i][j] = (f32x4)0.f;

    for (int k0 = 0; k0 < K; k0 += 64) {
        // ---- stage A: wave covers rows [wid*32, wid*32+32)
#pragma unroll
        for (int i = 0; i < 4; ++i) {
            const int r = wid * 32 + i * 8 + srow;
            const short8 v = *reinterpret_cast<const short8*>(
                &A[(size_t)(m0 + r) * K + k0 + sswz * 8]);
            *reinterpret_cast<short8*>(&As[r * 64 + schunk * 8]) = v;
        }
        // ---- stage B: wave covers cols [wid*16, wid*16+16)
#pragma unroll
        for (int i = 0; i < 2; ++i) {
            const int r = wid * 16 + i * 8 + srow;
            const short8 v = *reinterpret_cast<const short8*>(
                &BT[(size_t)(n0 + r) * K + k0 + sswz * 8]);
            *reinterpret_cast<short8*>(&Bs[r * 64 + schunk * 8]) = v;
        }
        __syncthreads();

#pragma unroll
        for (int ks = 0; ks < 2; ++ks) {
            short8 af[4], bf[2];
            const int c = ks * 4 + (lane >> 4);
#pragma unroll
            for (int fm = 0; fm < 4; ++fm) {
                const int r = wm * 64 + fm * 16 + (lane & 15);
                af[fm] = *reinterpret_cast<const short8*>(
                    &As[r * 64 + (c ^ (r & 7)) * 8]);
            }
#pragma unroll
            for (int fn = 0; fn < 2; ++fn) {
                const int r = wn * 32 + fn * 16 + (lane & 15);
                bf[fn] = *reinterpret_cast<const short8*>(
                    &Bs[r * 64 + (c ^ (r & 7)) * 8]);
            }
#pragma unroll
            for (int fm = 0; fm < 4; ++fm)
#pragma unroll
                for (int fn = 0; fn < 2; ++fn)
                    acc[fm][fn] = __builtin_amdgcn_mfma_f32_16x16x32_bf16(
                        af[fm], bf[fn], acc[fm][fn], 0, 0, 0);
        }
        __syncthreads();
    }

    // ---- epilogue ----
    // C/D layout: col = lane&15, row = (lane>>4)*4 + reg   [m89-verified]
#pragma unroll
    for (int fn = 0; fn < 2; ++fn) {
        const int col = n0 + wn * 32 + fn * 16 + (lane & 15);
        const float bv = bias[col];
#pragma unroll
        for (int fm = 0; fm < 4; ++fm) {
            const int rbase = m0 + wm * 64 + fm * 16 + (lane >> 4) * 4;
#pragma unroll
            for (int e = 0; e < 4; ++e) {
                const float v = acc[fm][fn][e] + bv;
                if (EPI == 0) {
                    unsigned short* h = (unsigned short*)outv;
                    h[(size_t)(rbase + e) * N + col] = f2bf(fmaxf(v, 0.f));
                } else {
                    float* out = (float*)outv;
                    const int p = col >> 10;
                    const int w = col & 1023;
                    out[(size_t)p * EDGES + (size_t)(rbase + e) * OUT_DIM + w] =
                        __expf(v);
                }
            }
        }
    }
}

// ================= binning: histogram + scatter (unchanged) ================
// record u32 = (seg & 511) << 23 | w
__global__ __launch_bounds__(256) void hist_scatter_kernel(
    const int* __restrict__ idx, int w0, unsigned* __restrict__ P,
    unsigned* __restrict__ cursor)
{
    __shared__ unsigned hist[BINS];
    __shared__ unsigned offs[BINS];
    const int tid = threadIdx.x;
    const int base = w0 + blockIdx.x * CHUNK;

    for (int b = tid; b < BINS; b += 256) { hist[b] = 0; offs[b] = 0; }
    __syncthreads();

#pragma unroll 4
    for (int i = 0; i < CHUNK / 256; ++i) {
        const int seg = idx[base + i * 256 + tid];
        atomicAdd(&hist[seg >> 9], 1u);
    }
    __syncthreads();

    for (int b = tid; b < BINS; b += 256)
        hist[b] = atomicAdd(&cursor[b], hist[b]);
    __syncthreads();

#pragma unroll 4
    for (int i = 0; i < CHUNK / 256; ++i) {
        const int w = base + i * 256 + tid;
        const int seg = idx[w];
        const int b = seg >> 9;
        const unsigned o = atomicAdd(&offs[b], 1u);
        P[(size_t)b * BIN_CAP + hist[b] + o] =
            ((unsigned)(seg & 511) << 23) | (unsigned)w;
    }
}

// ================= per-bin reduce (unchanged) ==============================
__global__ __launch_bounds__(256) void reduce01_kernel(
    const unsigned* __restrict__ P, const unsigned* __restrict__ cursor,
    const float* __restrict__ out, float2* __restrict__ s01, int accum)
{
    __shared__ float sub0[SEGS_PER_BIN];
    __shared__ float sub1[SEGS_PER_BIN];
    const int b = blockIdx.x;
    const int tid = threadIdx.x;
    for (int i = tid; i < SEGS_PER_BIN; i += 256) { sub0[i] = 0.f; sub1[i] = 0.f; }
    __syncthreads();

    const int cnt = (int)cursor[b];
    const unsigned* rec = &P[(size_t)b * BIN_CAP];
    for (int i = tid; i < cnt; i += 256) {
        const unsigned r = rec[i];
        const int w = r & 0x7FFFFF;
        const int sl = r >> 23;
        atomicAdd(&sub0[sl], out[w]);
        atomicAdd(&sub1[sl], out[EDGES + w]);
    }
    __syncthreads();

    for (int i = tid; i < SEGS_PER_BIN; i += 256) {
        const int seg = b * SEGS_PER_BIN + i;
        float2 v = make_float2(sub0[i], sub1[i]);
        if (accum) { const float2 p = s01[seg]; v.x += p.x; v.y += p.y; }
        s01[seg] = v;
    }
}

__global__ __launch_bounds__(256) void reduce2_kernel(
    const unsigned* __restrict__ P, const unsigned* __restrict__ cursor,
    const float* __restrict__ out, float* __restrict__ s2, int accum)
{
    __shared__ float sub[SEGS_PER_BIN];
    const int b = blockIdx.x;
    const int tid = threadIdx.x;
    for (int i = tid; i < SEGS_PER_BIN; i += 256) sub[i] = 0.f;
    __syncthreads();

    const int cnt = (int)cursor[b];
    const unsigned* rec = &P[(size_t)b * BIN_CAP];
    for (int i = tid; i < cnt; i += 256) {
        const unsigned r = rec[i];
        const int w = r & 0x7FFFFF;
        const int sl = r >> 23;
        atomicAdd(&sub[sl], out[2 * (size_t)EDGES + w]);
    }
    __syncthreads();

    for (int i = tid; i < SEGS_PER_BIN; i += 256) {
        const int seg = b * SEGS_PER_BIN + i;
        float v = sub[i];
        if (accum) v += s2[seg];
        s2[seg] = v;
    }
}

// ================= softmax finish (unchanged) ==============================
__global__ __launch_bounds__(256) void recip_kernel(float2* __restrict__ s01,
                                                    float* __restrict__ s2) {
    const int i = blockIdx.x * blockDim.x + threadIdx.x;
    if (i >= NSEG) return;
    const float2 v = s01[i];
    s01[i] = make_float2(1.f / v.x, 1.f / v.y);
    s2[i] = 1.f / s2[i];
}

__global__ __launch_bounds__(256) void segdiv_kernel(
    float* __restrict__ vals, const int* __restrict__ idx0,
    const int* __restrict__ idx1, const float2* __restrict__ r01,
    const float* __restrict__ r2) {
    const int w = blockIdx.x * blockDim.x + threadIdx.x;
    if (w >= EDGES) return;
    const float2 rv = r01[idx0[w]];
    const float rc = r2[idx1[w]];
    vals[w] *= rv.x;
    vals[EDGES + w] *= rv.y;
    vals[2 * (size_t)EDGES + w] *= rc;
}

// ===========================================================================
extern "C" void kernel_launch(void* const* d_in, const int* in_sizes, int n_in,
                              void* d_out, int out_size, void* d_ws,
                              size_t ws_size, hipStream_t stream) {
    const float* u2s = (const float*)d_in[0];
    const float* usr = (const float*)d_in[1];
    const float* srv = (const float*)d_in[2];
    const int* edge = (const int*)d_in[3];
    const float* W1 = (const float*)d_in[4];
    const float* b1 = (const float*)d_in[5];
    const float* W2 = (const float*)d_in[6];
    const float* b2 = (const float*)d_in[7];
    const float* W3 = (const float*)d_in[8];
    const float* b3 = (const float*)d_in[9];
    const float* W4 = (const float*)d_in[10];
    const float* b4 = (const float*)d_in[11];

    const int* idx0 = edge;
    const int* idx1 = edge + EDGES;

    // ws layout (max 38.4 MB; 48 MB proven available):
    //  [0, 24MB):  feats_bf16 [8192][1216] (19.9MB)  --later--> P (23.6MB)+cursor
    //  [24,28MB):  h1 bf16   --later--> s01 (with h2's slot, [24,32))
    //  [28,32MB):  h2 bf16
    //  [32,36MB):  h3 bf16   --later--> s2
    //  [36,~38.4): W1T, W2T, W3T, W4T (bf16)
    char* ws = (char*)d_ws;
    unsigned short* F = (unsigned short*)ws;
    unsigned* P = (unsigned*)ws;
    unsigned* cursor = P + (size_t)BINS * BIN_CAP;
    unsigned short* h1 = (unsigned short*)(ws + 24u * 1024 * 1024);
    unsigned short* h2 = (unsigned short*)(ws + 28u * 1024 * 1024);
    unsigned short* h3 = (unsigned short*)(ws + 32u * 1024 * 1024);
    float2* s01 = (float2*)(ws + 24u * 1024 * 1024);
    float* s2 = (float*)(ws + 32u * 1024 * 1024);
    unsigned short* w1t = (unsigned short*)(ws + 36u * 1024 * 1024);
    unsigned short* w2t = w1t + (size_t)HID * KPAD1;
    unsigned short* w3t = w2t + (size_t)HID * HID;
    unsigned short* w4t = w3t + (size_t)HID * HID;
    float* outp = (float*)d_out;

    const dim3 blk(256);

    // ---- prep: conversions ----
    convert_feats_kernel<<<(B_GRAPHS * 152) / 256, blk, 0, stream>>>(u2s, usr,
                                                                     srv, F);
    convert_wT_kernel<<<(HID * KPAD1 + 255) / 256, blk, 0, stream>>>(
        W1, w1t, IN_DIM, HID, KPAD1);
    convert_wT_kernel<<<(HID * HID + 255) / 256, blk, 0, stream>>>(
        W2, w2t, HID, HID, HID);
    convert_wT_kernel<<<(HID * HID + 255) / 256, blk, 0, stream>>>(
        W3, w3t, HID, HID, HID);
    convert_wT_kernel<<<(3 * OUT_DIM * HID + 255) / 256, blk, 0, stream>>>(
        W4, w4t, HID, 3 * OUT_DIM, HID);

    // ---- MLP (bf16 MFMA) ----
    gemm_bf16_kernel<0><<<dim3(HID / 64, B_GRAPHS / 128), blk, 0, stream>>>(
        F, w1t, b1, h1, HID, KPAD1);
    gemm_bf16_kernel<0><<<dim3(HID / 64, B_GRAPHS / 128), blk, 0, stream>>>(
        h1, w2t, b2, h2, HID, HID);
    gemm_bf16_kernel<0><<<dim3(HID / 64, B_GRAPHS / 128), blk, 0, stream>>>(
        h2, w3t, b3, h3, HID, HID);
    gemm_bf16_kernel<1><<<dim3(3 * OUT_DIM / 64, B_GRAPHS / 128), blk, 0,
                          stream>>>(h3, w4t, b4, outp, 3 * OUT_DIM, HID);

    // ---- segment sums via bin-scatter-reduce ----
    for (int h = 0; h < 2; ++h) {
        hipMemsetAsync(cursor, 0, BINS * sizeof(unsigned), stream);
        hist_scatter_kernel<<<HIST_BLOCKS, blk, 0, stream>>>(idx0, h * HALF, P,
                                                             cursor);
        reduce01_kernel<<<BINS, blk, 0, stream>>>(P, cursor, outp, s01, h);
    }
    for (int h = 0; h < 2; ++h) {
        hipMemsetAsync(cursor, 0, BINS * sizeof(unsigned), stream);
        hist_scatter_kernel<<<HIST_BLOCKS, blk, 0, stream>>>(idx1, h * HALF, P,
                                                             cursor);
        reduce2_kernel<<<BINS, blk, 0, stream>>>(P, cursor, outp, s2, h);
    }

    recip_kernel<<<(NSEG + 255) / 256, blk, 0, stream>>>(s01, s2);
    segdiv_kernel<<<(EDGES + 255) / 256, blk, 0, stream>>>(outp, idx0, idx1,
                                                           s01, s2);
}